// Round 12
// baseline (297.169 us; speedup 1.0000x reference)
//
#include <hip/hip_runtime.h>
#include <math.h>

typedef __bf16 bf16;
typedef bf16 bf16x8 __attribute__((ext_vector_type(8)));
typedef bf16 bf16x4 __attribute__((ext_vector_type(4)));
typedef float f32x4 __attribute__((ext_vector_type(4)));

#define BB 2
#define SS 2048
#define NKVE 1152   // 512 k + 512 v + 128 emb
#define QSCALE (0.08838834764831845f * 1.4426950408889634f)  // 1/sqrt(128)*log2(e)

__device__ __forceinline__ float waveAllReduceSum(float v) {
#pragma unroll
  for (int o = 1; o < 64; o <<= 1) v += __shfl_xor(v, o, 64);
  return v;
}

__device__ __forceinline__ int xcd_swz(int orig, int nwg) {
  return (orig & 7) * (nwg >> 3) + (orig >> 3);
}

__device__ __forceinline__ void gload16(const bf16* g, bf16* l) {
  __builtin_amdgcn_global_load_lds((const __attribute__((address_space(1))) void*)g,
                                   (__attribute__((address_space(3))) void*)l, 16, 0, 0);
}

// ---------------- fused weight prep: cvt hidden + 5 transposes ----------------
__device__ __forceinline__ void do_transpose(bf16 (*tile)[72], const float* __restrict__ W,
                                             bf16* __restrict__ WT, int K, int N, int rowOff,
                                             int bx, int by, int t) {
  int n0 = bx * 64, k0 = by * 64;
  {
    int c4 = (t & 15) * 4, r = t >> 4;
#pragma unroll
    for (int p = 0; p < 4; p++) {
      int row = p * 16 + r;
      float4 v = *reinterpret_cast<const float4*>(W + (size_t)(k0 + row) * N + n0 + c4);
      bf16x4 o = {(bf16)v.x, (bf16)v.y, (bf16)v.z, (bf16)v.w};
      *reinterpret_cast<bf16x4*>(&tile[row][c4]) = o;
    }
  }
  __syncthreads();
  {
    int ln = t & 7, n = t >> 3;
#pragma unroll
    for (int p = 0; p < 2; p++) {
      int nn = p * 32 + n;
      bf16x8 o;
#pragma unroll
      for (int j = 0; j < 8; j++) o[j] = tile[ln * 8 + j][nn];
      *reinterpret_cast<bf16x8*>(WT + (size_t)(rowOff + n0 + nn) * K + k0 + ln * 8) = o;
    }
  }
  __syncthreads();
}

__global__ __launch_bounds__(256) void prep_weights(const float* __restrict__ hidden,
                                                    const float* __restrict__ Wq,
                                                    const float* __restrict__ Wk,
                                                    const float* __restrict__ Wv,
                                                    const float* __restrict__ Wr,
                                                    const float* __restrict__ Wo,
                                                    bf16* __restrict__ hb,
                                                    bf16* __restrict__ WTall,
                                                    bf16* __restrict__ WoT) {
  __shared__ bf16 tile[64][72];
  int id = blockIdx.x, t = threadIdx.x;
  if (id < 4096) {
    int i = (id * 256 + t) * 8;
    float4 v0 = *reinterpret_cast<const float4*>(hidden + i);
    float4 v1 = *reinterpret_cast<const float4*>(hidden + i + 4);
    bf16x8 o = {(bf16)v0.x, (bf16)v0.y, (bf16)v0.z, (bf16)v0.w,
                (bf16)v1.x, (bf16)v1.y, (bf16)v1.z, (bf16)v1.w};
    *reinterpret_cast<bf16x8*>(hb + i) = o;
    return;
  }
  int id2 = id - 4096;
  if (id2 < 2048) { do_transpose(tile, Wq, WTall, 2048, 4096, 0, id2 & 63, id2 >> 6, t); return; }
  id2 -= 2048;
  if (id2 < 256) { do_transpose(tile, Wk, WTall, 2048, 512, 4096, id2 & 7, id2 >> 3, t); return; }
  id2 -= 256;
  if (id2 < 256) { do_transpose(tile, Wv, WTall, 2048, 512, 4608, id2 & 7, id2 >> 3, t); return; }
  id2 -= 256;
  if (id2 < 64) { do_transpose(tile, Wr, WTall, 2048, 128, 5120, id2 & 1, id2 >> 1, t); return; }
  id2 -= 64;
  do_transpose(tile, Wo, WoT, 2048, 2048, 0, id2 & 31, id2 >> 5, t);
}

// ---------------- m97-style GEMM (kve): C = A @ Bt^T ----------------
template <typename CT>
__global__ __launch_bounds__(256) void gemm_bt(const bf16* __restrict__ A,
                                               const bf16* __restrict__ Bt,
                                               CT* __restrict__ C, int M, int N, int K) {
  __shared__ bf16 lA[128 * 64];
  __shared__ bf16 lB[128 * 64];
  const int nbx = N >> 7;
  int wg = xcd_swz(blockIdx.x, gridDim.x);
  int bx = wg % nbx, by = wg / nbx;
  const int t = threadIdx.x;
  const int l = t & 63, w = t >> 6;
  const int wr = w >> 1, wc = w & 1;
  const int lr = l & 15, lhi = l >> 4;

  f32x4 acc[4][4];
#pragma unroll
  for (int m = 0; m < 4; m++)
#pragma unroll
    for (int n = 0; n < 4; n++) acc[m][n] = f32x4{0.f, 0.f, 0.f, 0.f};

  const int rowA0 = by * 128, rowB0 = bx * 128;
  const int nkt = K >> 6;
  for (int kt = 0; kt < nkt; ++kt) {
    __syncthreads();
#pragma unroll
    for (int it = 0; it < 4; ++it) {
      int slot = it * 256 + t;
      int row = slot >> 3, sl = slot & 7;
      gload16(A + (size_t)(rowA0 + row) * K + kt * 64 + ((sl ^ (row & 7)) << 3), lA + slot * 8);
      gload16(Bt + (size_t)(rowB0 + row) * K + kt * 64 + ((sl ^ (row & 7)) << 3), lB + slot * 8);
    }
    __syncthreads();
#pragma unroll
    for (int kc = 0; kc < 2; ++kc) {
      bf16x8 af[4], bg[4];
#pragma unroll
      for (int m = 0; m < 4; m++) {
        int row = wr * 64 + m * 16 + lr;
        af[m] = *reinterpret_cast<const bf16x8*>((char*)lA + row * 128 + (((kc * 4 + lhi) ^ (row & 7)) << 4));
      }
#pragma unroll
      for (int n = 0; n < 4; n++) {
        int row = wc * 64 + n * 16 + lr;
        bg[n] = *reinterpret_cast<const bf16x8*>((char*)lB + row * 128 + (((kc * 4 + lhi) ^ (row & 7)) << 4));
      }
      __builtin_amdgcn_s_setprio(1);
#pragma unroll
      for (int m = 0; m < 4; m++)
#pragma unroll
        for (int n = 0; n < 4; n++)
          acc[m][n] = __builtin_amdgcn_mfma_f32_16x16x32_bf16(af[m], bg[n], acc[m][n], 0, 0, 0);
      __builtin_amdgcn_s_setprio(0);
    }
  }
#pragma unroll
  for (int m = 0; m < 4; m++)
#pragma unroll
    for (int n = 0; n < 4; n++)
#pragma unroll
      for (int r = 0; r < 4; r++) {
        int grow = rowA0 + wr * 64 + m * 16 + lhi * 4 + r;
        int gcol = rowB0 + wc * 64 + n * 16 + lr;
        C[(size_t)grow * N + gcol] = (CT)acc[m][n][r];
      }
}

// ---------------- q/gate GEMM: 256x256, 8 waves, 2-deep counted-vmcnt pipeline ----------------
__global__ __launch_bounds__(512, 2) void gemm_qg(const bf16* __restrict__ A,
                                                  const bf16* __restrict__ Bt,
                                                  bf16* __restrict__ Cq) {
  __shared__ bf16 lA[2][256 * 64];
  __shared__ bf16 lB[2][256 * 64];
  int wg = xcd_swz(blockIdx.x, 256);
  int bx = wg & 15, by = wg >> 4;
  const int t = threadIdx.x;
  const int l = t & 63, w = t >> 6;
  const int wm = w >> 2, wn = w & 3;
  const int lr = l & 15, lhi = l >> 4;
  const int K = 2048;

  f32x4 acc[8][4];
#pragma unroll
  for (int m = 0; m < 8; m++)
#pragma unroll
    for (int n = 0; n < 4; n++) acc[m][n] = f32x4{0.f, 0.f, 0.f, 0.f};

  const int rowA0 = by * 256, rowB0 = bx * 256;

  auto stage = [&](int buf, int kt) {
#pragma unroll
    for (int it = 0; it < 4; ++it) {
      int slot = it * 512 + t;
      int row = slot >> 3, sl = slot & 7;
      gload16(A + (size_t)(rowA0 + row) * K + kt * 64 + ((sl ^ (row & 7)) << 3), lA[buf] + slot * 8);
      gload16(Bt + (size_t)(rowB0 + row) * K + kt * 64 + ((sl ^ (row & 7)) << 3), lB[buf] + slot * 8);
    }
  };

  stage(0, 0);
  stage(1, 1);

  for (int kt = 0; kt < 32; ++kt) {
    int cur = kt & 1;
    if (kt < 31) {
      asm volatile("s_waitcnt vmcnt(8)" ::: "memory");
    } else {
      asm volatile("s_waitcnt vmcnt(0)" ::: "memory");
    }
    __builtin_amdgcn_sched_barrier(0);
    __builtin_amdgcn_s_barrier();
    __builtin_amdgcn_sched_barrier(0);

#pragma unroll
    for (int ks = 0; ks < 2; ++ks) {
      bf16x8 bg[4];
#pragma unroll
      for (int n = 0; n < 4; n++) {
        int row = wn * 64 + n * 16 + lr;
        bg[n] = *reinterpret_cast<const bf16x8*>((char*)lB[cur] + row * 128 + (((ks * 4 + lhi) ^ (row & 7)) << 4));
      }
#pragma unroll
      for (int mh = 0; mh < 2; ++mh) {
        bf16x8 af[4];
#pragma unroll
        for (int m = 0; m < 4; m++) {
          int row = wm * 128 + (mh * 4 + m) * 16 + lr;
          af[m] = *reinterpret_cast<const bf16x8*>((char*)lA[cur] + row * 128 + (((ks * 4 + lhi) ^ (row & 7)) << 4));
        }
        __builtin_amdgcn_s_setprio(1);
#pragma unroll
        for (int m = 0; m < 4; m++)
#pragma unroll
          for (int n = 0; n < 4; n++)
            acc[mh * 4 + m][n] = __builtin_amdgcn_mfma_f32_16x16x32_bf16(af[m], bg[n], acc[mh * 4 + m][n], 0, 0, 0);
        __builtin_amdgcn_s_setprio(0);
      }
    }

    asm volatile("s_waitcnt lgkmcnt(0)" ::: "memory");
    __builtin_amdgcn_sched_barrier(0);
    __builtin_amdgcn_s_barrier();
    __builtin_amdgcn_sched_barrier(0);
    if (kt + 2 < 32) stage(cur, kt + 2);
  }

#pragma unroll
  for (int m = 0; m < 8; m++)
#pragma unroll
    for (int n = 0; n < 4; n++)
#pragma unroll
      for (int r = 0; r < 4; r++) {
        int grow = rowA0 + wm * 128 + m * 16 + lhi * 4 + r;
        int gcol = rowB0 + wn * 64 + n * 16 + lr;
        Cq[(size_t)grow * 4096 + gcol] = (bf16)acc[m][n][r];
      }
}

// ---------------- out GEMM: 256x128, 8 waves, 2-deep counted-vmcnt pipeline ----------------
__global__ __launch_bounds__(512, 2) void gemm_out(const bf16* __restrict__ A,
                                                   const bf16* __restrict__ Bt,
                                                   float* __restrict__ C) {
  __shared__ bf16 lA[2][256 * 64];
  __shared__ bf16 lB[2][128 * 64];
  int wg = xcd_swz(blockIdx.x, 256);
  int bx = wg & 15, by = wg >> 4;
  const int t = threadIdx.x;
  const int l = t & 63, w = t >> 6;
  const int wm = w >> 1, wn = w & 1;
  const int lr = l & 15, lhi = l >> 4;
  const int K = 2048;

  f32x4 acc[4][4];
#pragma unroll
  for (int m = 0; m < 4; m++)
#pragma unroll
    for (int n = 0; n < 4; n++) acc[m][n] = f32x4{0.f, 0.f, 0.f, 0.f};

  const int rowA0 = by * 256, rowB0 = bx * 128;

  auto stage = [&](int buf, int kt) {
#pragma unroll
    for (int it = 0; it < 4; ++it) {
      int slot = it * 512 + t;
      int row = slot >> 3, sl = slot & 7;
      gload16(A + (size_t)(rowA0 + row) * K + kt * 64 + ((sl ^ (row & 7)) << 3), lA[buf] + slot * 8);
    }
#pragma unroll
    for (int it = 0; it < 2; ++it) {
      int slot = it * 512 + t;
      int row = slot >> 3, sl = slot & 7;
      gload16(Bt + (size_t)(rowB0 + row) * K + kt * 64 + ((sl ^ (row & 7)) << 3), lB[buf] + slot * 8);
    }
  };

  stage(0, 0);
  stage(1, 1);

  for (int kt = 0; kt < 32; ++kt) {
    int cur = kt & 1;
    if (kt < 31) {
      asm volatile("s_waitcnt vmcnt(6)" ::: "memory");
    } else {
      asm volatile("s_waitcnt vmcnt(0)" ::: "memory");
    }
    __builtin_amdgcn_sched_barrier(0);
    __builtin_amdgcn_s_barrier();
    __builtin_amdgcn_sched_barrier(0);

#pragma unroll
    for (int ks = 0; ks < 2; ++ks) {
      bf16x8 bg[4];
#pragma unroll
      for (int n = 0; n < 4; n++) {
        int row = wn * 64 + n * 16 + lr;
        bg[n] = *reinterpret_cast<const bf16x8*>((char*)lB[cur] + row * 128 + (((ks * 4 + lhi) ^ (row & 7)) << 4));
      }
      bf16x8 af[4];
#pragma unroll
      for (int m = 0; m < 4; m++) {
        int row = wm * 64 + m * 16 + lr;
        af[m] = *reinterpret_cast<const bf16x8*>((char*)lA[cur] + row * 128 + (((ks * 4 + lhi) ^ (row & 7)) << 4));
      }
      __builtin_amdgcn_s_setprio(1);
#pragma unroll
      for (int m = 0; m < 4; m++)
#pragma unroll
        for (int n = 0; n < 4; n++)
          acc[m][n] = __builtin_amdgcn_mfma_f32_16x16x32_bf16(af[m], bg[n], acc[m][n], 0, 0, 0);
      __builtin_amdgcn_s_setprio(0);
    }

    asm volatile("s_waitcnt lgkmcnt(0)" ::: "memory");
    __builtin_amdgcn_sched_barrier(0);
    __builtin_amdgcn_s_barrier();
    __builtin_amdgcn_sched_barrier(0);
    if (kt + 2 < 32) stage(cur, kt + 2);
  }

#pragma unroll
  for (int m = 0; m < 4; m++)
#pragma unroll
    for (int n = 0; n < 4; n++)
#pragma unroll
      for (int r = 0; r < 4; r++) {
        int grow = rowA0 + wm * 64 + m * 16 + lhi * 4 + r;
        int gcol = rowB0 + wn * 64 + n * 16 + lr;
        C[(size_t)grow * 2048 + gcol] = acc[m][n][r];
      }
}

// ---------------- Threefry-2x32 (JAX), key (0,42) -> gumbel ----------------
__device__ __forceinline__ unsigned rotl32(unsigned x, int r) { return (x << r) | (x >> (32 - r)); }

__device__ __forceinline__ float gumbel42(unsigned i) {
  const unsigned half = (unsigned)(BB * SS * 128) / 2u;  // 262144
  unsigned x0, x1;
  int word;
  if (i < half) { x0 = i; x1 = i + half; word = 0; }
  else          { x0 = i - half; x1 = i; word = 1; }
  const unsigned k0 = 0u, k1 = 42u;
  const unsigned k2 = k0 ^ k1 ^ 0x1BD11BDAu;
  x0 += k0; x1 += k1;
#define TF_R(r) { x0 += x1; x1 = rotl32(x1, r); x1 ^= x0; }
  TF_R(13) TF_R(15) TF_R(26) TF_R(6)
  x0 += k1; x1 += k2 + 1u;
  TF_R(17) TF_R(29) TF_R(16) TF_R(24)
  x0 += k2; x1 += k0 + 2u;
  TF_R(13) TF_R(15) TF_R(26) TF_R(6)
  x0 += k0; x1 += k1 + 3u;
  TF_R(17) TF_R(29) TF_R(16) TF_R(24)
  x0 += k1; x1 += k2 + 4u;
  TF_R(13) TF_R(15) TF_R(26) TF_R(6)
  x0 += k2; x1 += k0 + 5u;
#undef TF_R
  unsigned bits = word ? x1 : x0;
  float u = __uint_as_float((bits >> 9) | 0x3f800000u) - 1.0f;
  float ex = -log1pf(-u);
  return -logf(ex);
}

// ---------------- mask kernel (reads emb from kve[.., 1024..1151]) ----------------
__global__ __launch_bounds__(128) void mask_kernel(const bf16* __restrict__ kve,
                                                   const float* __restrict__ rnn,
                                                   const float* __restrict__ lng,
                                                   const float* __restrict__ lnb,
                                                   const float* __restrict__ Wd,
                                                   bf16* __restrict__ maskb) {
  int row = blockIdx.x;
  int t = threadIdx.x;
  int l = t & 63, w = t >> 6;
  __shared__ float redm[2], redv[2], gsh[128];
  float e = (float)kve[(size_t)row * NKVE + 1024 + t] + rnn[t];
  float s1 = waveAllReduceSum(e);
  if (l == 0) redm[w] = s1;
  __syncthreads();
  float mu = (redm[0] + redm[1]) * (1.0f / 128.0f);
  float dv = (e - mu) * (e - mu);
  float s2 = waveAllReduceSum(dv);
  if (l == 0) redv[w] = s2;
  __syncthreads();
  float var = (redv[0] + redv[1]) * (1.0f / 128.0f);
  float ln = (e - mu) * rsqrtf(var + 1e-5f) * lng[t] + lnb[t];
  float g = 0.5f * ln * (1.0f + erff(ln * 0.7071067811865475f));
  gsh[t] = g;
  __syncthreads();
  float logit = 0.f;
#pragma unroll 8
  for (int e2 = 0; e2 < 128; e2++) logit += gsh[e2] * Wd[e2 * 128 + t];
  float gum = gumbel42((unsigned)(row * 128 + t));
  float x = (logit + gum + 3.0f) * 2.5f;
  float y = 1.0f / (1.0f + expf(-x));
  maskb[(size_t)row * 128 + t] = (bf16)rintf(y);
}

// ---------------- QKV prep (k + vt from kve) ----------------
__global__ __launch_bounds__(256) void qkv_prep(const bf16* __restrict__ kve,
                                                const bf16* __restrict__ maskb,
                                                const float* __restrict__ kw,
                                                const float* __restrict__ cosT,
                                                const float* __restrict__ sinT,
                                                bf16* __restrict__ wk,
                                                bf16* __restrict__ wvt) {
  int id = blockIdx.x, t = threadIdx.x;
  if (id < 1024) {
    int g = t >> 4, ln = t & 15;
    int hr = id * 16 + g;
    int kv = hr & 3, row = hr >> 2;
    int b = row >> 11, s = row & 2047;
    const bf16* kp = kve + (size_t)row * NKVE + kv * 128 + ln * 8;
    bf16x8 k8 = *reinterpret_cast<const bf16x8*>(kp);
    bf16x8 m8 = *reinterpret_cast<const bf16x8*>(maskb + (size_t)row * 128 + ln * 8);
    float kf[8], ss = 0.f;
#pragma unroll
    for (int j = 0; j < 8; j++) { kf[j] = (float)k8[j]; ss += kf[j] * kf[j]; }
#pragma unroll
    for (int o = 1; o < 16; o <<= 1) ss += __shfl_xor(ss, o, 16);
    float rinv = rsqrtf(ss * (1.0f / 128.0f) + 1e-6f);
    alignas(16) float wv[8];
    const float4* kw4 = reinterpret_cast<const float4*>(kw);
    *reinterpret_cast<float4*>(&wv[0]) = kw4[ln * 2];
    *reinterpret_cast<float4*>(&wv[4]) = kw4[ln * 2 + 1];
    float km[8];
#pragma unroll
    for (int j = 0; j < 8; j++) km[j] = kf[j] * rinv * (1.0f + wv[j]) * (float)m8[j];
    alignas(16) float c8[8], s8[8];
    if (ln < 8) {
      const float4* c4 = reinterpret_cast<const float4*>(cosT + (size_t)row * 64);
      const float4* sn4 = reinterpret_cast<const float4*>(sinT + (size_t)row * 64);
      *reinterpret_cast<float4*>(&c8[0]) = c4[ln * 2];
      *reinterpret_cast<float4*>(&c8[4]) = c4[ln * 2 + 1];
      *reinterpret_cast<float4*>(&s8[0]) = sn4[ln * 2];
      *reinterpret_cast<float4*>(&s8[4]) = sn4[ln * 2 + 1];
    }
    float po[8];
#pragma unroll
    for (int j = 0; j < 8; j++) po[j] = __shfl_xor(km[j], 4, 16);
    bf16x8 ok;
#pragma unroll
    for (int j = 0; j < 8; j++) {
      float ov;
      if (ln < 4) ov = km[j] * c8[j] - po[j] * s8[j];
      else if (ln < 8) ov = km[j] * c8[j] + po[j] * s8[j];
      else ov = km[j];
      ok[j] = (bf16)ov;
    }
    *reinterpret_cast<bf16x8*>(wk + ((size_t)((b * 4 + kv) * 2048 + s)) * 128 + ln * 8) = ok;
    return;
  }
  {
    __shared__ bf16 tl[64][72];
    int vb = id - 1024;
    int dt = vb & 1;
    int st = (vb >> 1) & 31;
    int bkv = vb >> 6;
    int b = bkv >> 2, kv = bkv & 3;
    int tx = t & 63, ty = t >> 6;
    int s0 = st * 64, d0 = dt * 64;
#pragma unroll
    for (int i = 0; i < 16; i++) {
      int srow = ty + i * 4;
      tl[srow][tx] = kve[(size_t)(b * 2048 + s0 + srow) * NKVE + 512 + kv * 128 + d0 + tx];
    }
    __syncthreads();
#pragma unroll
    for (int i = 0; i < 16; i++) {
      int drow = ty + i * 4;
      wvt[(size_t)((b * 4 + kv) * 128 + d0 + drow) * 2048 + s0 + tx] = tl[tx][drow];
    }
  }
}

// ---------------- flash attention v8: 512 blocks (one q128-tile each), 2 blocks/CU ----------------
// qi schedule: heavy-first LPT + rest/rest+32 pair to 17-tile sum under static stacking.
__global__ __launch_bounds__(512) void attn_kernel(const bf16* __restrict__ qg,
                                                   const bf16* __restrict__ wk,
                                                   const bf16* __restrict__ wvt,
                                                   const bf16* __restrict__ maskb,
                                                   const float* __restrict__ qw,
                                                   const float* __restrict__ cosT,
                                                   const float* __restrict__ sinT,
                                                   bf16* __restrict__ wattn) {
  __shared__ bf16 lK[2][64 * 128];
  __shared__ bf16 lV[2][128 * 64];
  __shared__ bf16 lP[8][16 * 64];
  int bid = blockIdx.x;
  int grp = bid & 7;          // XCD group = b*4+kvh
  int b = grp >> 2, kvh = grp & 3;
  int rest = bid >> 3;        // 0..63
  int hsub = rest & 3;
  int qidx = rest >> 2;       // 0..15
  int qi = (qidx < 8) ? (15 - 2 * qidx) : (2 * (qidx - 8));
  int h = kvh * 4 + hsub;
  int bh = b * 16 + h;
  int t = threadIdx.x, l = t & 63, w = t >> 6;
  int lr = l & 15, lhi = l >> 4;

  const bf16* kbase = wk + (size_t)((b * 4 + kvh) * 2048) * 128;
  const bf16* vbase = wvt + (size_t)((b * 4 + kvh) * 128) * 2048;
  char* pb = (char*)(&lP[w][0]);

  const int nkv = 2 * qi + 2;

  auto stage = [&](int buf, int tt) {
#pragma unroll
    for (int it = 0; it < 2; ++it) {
      int slot = it * 512 + t;
      int row = slot >> 4, sl = slot & 15;
      gload16(kbase + (size_t)(tt * 64 + row) * 128 + ((sl ^ (row & 7)) << 3), lK[buf] + slot * 8);
      int row2 = slot >> 3, sl2 = slot & 7;
      gload16(vbase + (size_t)row2 * 2048 + tt * 64 + ((sl2 ^ (row2 & 7)) << 3), lV[buf] + slot * 8);
    }
  };

  bf16x8 aq[4];
  f32x4 oacc[8];
  float l_run;

  // in-register Q prep: lane holds d = kc*32 + lhi*8 + j; RoPE partner is kc 0<->1.
  {
    int srow = qi * 128 + w * 16 + lr;
    int grow = b * 2048 + srow;
    const bf16* qp = qg + (size_t)grow * 4096 + h * 256;
    int dbase = lhi * 8;
    float qf[4][8];
    float ss = 0.f;
#pragma unroll
    for (int kc = 0; kc < 4; kc++) {
      bf16x8 v = *reinterpret_cast<const bf16x8*>(qp + kc * 32 + dbase);
#pragma unroll
      for (int j = 0; j < 8; j++) { qf[kc][j] = (float)v[j]; ss += qf[kc][j] * qf[kc][j]; }
    }
    ss += __shfl_xor(ss, 16, 64);
    ss += __shfl_xor(ss, 32, 64);
    float rinv = rsqrtf(ss * (1.0f / 128.0f) + 1e-6f);
    const bf16* mrow = maskb + (size_t)grow * 128;
    float qm[4][8];
#pragma unroll
    for (int kc = 0; kc < 4; kc++) {
      bf16x8 m8 = *reinterpret_cast<const bf16x8*>(mrow + kc * 32 + dbase);
      alignas(16) float wv[8];
      *reinterpret_cast<float4*>(&wv[0]) = *reinterpret_cast<const float4*>(qw + kc * 32 + dbase);
      *reinterpret_cast<float4*>(&wv[4]) = *reinterpret_cast<const float4*>(qw + kc * 32 + dbase + 4);
#pragma unroll
      for (int j = 0; j < 8; j++) qm[kc][j] = qf[kc][j] * rinv * (1.0f + wv[j]) * (float)m8[j];
    }
    const float* crow = cosT + (size_t)grow * 64;
    const float* srw = sinT + (size_t)grow * 64;
    alignas(16) float c0[8], c1[8], s0[8], s1[8];
    *reinterpret_cast<float4*>(&c0[0]) = *reinterpret_cast<const float4*>(crow + dbase);
    *reinterpret_cast<float4*>(&c0[4]) = *reinterpret_cast<const float4*>(crow + dbase + 4);
    *reinterpret_cast<float4*>(&c1[0]) = *reinterpret_cast<const float4*>(crow + 32 + dbase);
    *reinterpret_cast<float4*>(&c1[4]) = *reinterpret_cast<const float4*>(crow + 32 + dbase + 4);
    *reinterpret_cast<float4*>(&s0[0]) = *reinterpret_cast<const float4*>(srw + dbase);
    *reinterpret_cast<float4*>(&s0[4]) = *reinterpret_cast<const float4*>(srw + dbase + 4);
    *reinterpret_cast<float4*>(&s1[0]) = *reinterpret_cast<const float4*>(srw + 32 + dbase);
    *reinterpret_cast<float4*>(&s1[4]) = *reinterpret_cast<const float4*>(srw + 32 + dbase + 4);
#pragma unroll
    for (int j = 0; j < 8; j++) {
      float o0 = qm[0][j] * c0[j] - qm[1][j] * s0[j];
      float o1 = qm[1][j] * c1[j] + qm[0][j] * s1[j];
      aq[0][j] = (bf16)(o0 * QSCALE);
      aq[1][j] = (bf16)(o1 * QSCALE);
      aq[2][j] = (bf16)(qm[2][j] * QSCALE);
      aq[3][j] = (bf16)(qm[3][j] * QSCALE);
    }
  }

#pragma unroll
  for (int db = 0; db < 8; db++) oacc[db] = f32x4{0.f, 0.f, 0.f, 0.f};
  l_run = 0.f;

  stage(0, 0);
  __syncthreads();
  int cur = 0;
  int qrow0 = qi * 128 + w * 16;

  for (int i = 0; i < nkv; ++i) {
    if (i + 1 < nkv) stage(cur ^ 1, i + 1);

    // QK^T (swapped): S[k local][q = lr]
    f32x4 sacc[4];
#pragma unroll
    for (int j = 0; j < 4; j++) sacc[j] = f32x4{0.f, 0.f, 0.f, 0.f};
    __builtin_amdgcn_s_setprio(1);
#pragma unroll
    for (int kc = 0; kc < 4; kc++)
#pragma unroll
      for (int j = 0; j < 4; j++) {
        int row = j * 16 + lr;
        bf16x8 ak = *reinterpret_cast<const bf16x8*>((char*)lK[cur] + row * 256 + (((kc * 4 + lhi) ^ (row & 7)) << 4));
        sacc[j] = __builtin_amdgcn_mfma_f32_16x16x32_bf16(ak, aq[kc], sacc[j], 0, 0, 0);
      }
    __builtin_amdgcn_s_setprio(0);

    if (i * 64 + 63 > qrow0) {  // causal mask
      int qrow_g = qrow0 + lr;
#pragma unroll
      for (int j = 0; j < 4; j++)
#pragma unroll
        for (int r = 0; r < 4; r++) {
          int kg = i * 64 + j * 16 + lhi * 4 + r;
          if (kg > qrow_g) sacc[j][r] = -1e30f;
        }
    }

    // unshifted softmax numerator: |S| <= sqrt(128)*log2e = 16.4 strictly
    float p[4][4];
    float sj[4];
#pragma unroll
    for (int j = 0; j < 4; j++) {
#pragma unroll
      for (int r = 0; r < 4; r++) p[j][r] = exp2f(sacc[j][r]);
      sj[j] = (p[j][0] + p[j][1]) + (p[j][2] + p[j][3]);
    }
    l_run += (sj[0] + sj[1]) + (sj[2] + sj[3]);

    // P through per-wave LDS (swizzled), then PV
#pragma unroll
    for (int j = 0; j < 4; j++) {
      bf16x4 p4 = {(bf16)p[j][0], (bf16)p[j][1], (bf16)p[j][2], (bf16)p[j][3]};
      *reinterpret_cast<bf16x4*>(pb + lr * 128 + ((j * 32 + lhi * 8) ^ ((lr & 7) << 4))) = p4;
    }
    bf16x8 pa[2];
#pragma unroll
    for (int kc2 = 0; kc2 < 2; kc2++)
      pa[kc2] = *reinterpret_cast<const bf16x8*>(pb + lr * 128 + ((kc2 * 64 + lhi * 16) ^ ((lr & 7) << 4)));
    __builtin_amdgcn_s_setprio(1);
#pragma unroll
    for (int kc2 = 0; kc2 < 2; kc2++)
#pragma unroll
      for (int db = 0; db < 8; db++) {
        int row = db * 16 + lr;
        bf16x8 bv = *reinterpret_cast<const bf16x8*>((char*)lV[cur] + row * 128 + (((kc2 * 4 + lhi) ^ (row & 7)) << 4));
        oacc[db] = __builtin_amdgcn_mfma_f32_16x16x32_bf16(pa[kc2], bv, oacc[db], 0, 0, 0);
      }
    __builtin_amdgcn_s_setprio(0);

    __syncthreads();
    cur ^= 1;
  }

  // epilogue: reduce l, fuse sigmoid(gate) from raw qg
  float lsum = l_run;
  lsum += __shfl_xor(lsum, 16, 64);
  lsum += __shfl_xor(lsum, 32, 64);
  float linv[4];
#pragma unroll
  for (int r = 0; r < 4; r++) linv[r] = 1.0f / __shfl(lsum, lhi * 4 + r, 64);
#pragma unroll
  for (int r = 0; r < 4; r++) {
    int srow = qi * 128 + w * 16 + lhi * 4 + r;
    const bf16* grow_p = qg + (size_t)(b * 2048 + srow) * 4096 + h * 256 + 128;
#pragma unroll
    for (int db = 0; db < 8; db++) {
      int dcol = db * 16 + lr;
      float graw = (float)grow_p[dcol];
      float g = 1.0f / (1.0f + expf(-graw));
      float ov = oacc[db][r] * linv[r] * g;
      wattn[(size_t)(b * 2048 + srow) * 2048 + h * 128 + dcol] = (bf16)ov;
    }
  }
}

extern "C" void kernel_launch(void* const* d_in, const int* in_sizes, int n_in,
                              void* d_out, int out_size, void* d_ws, size_t ws_size,
                              hipStream_t stream) {
  const float* hidden = (const float*)d_in[0];
  const float* cosT = (const float*)d_in[1];
  const float* sinT = (const float*)d_in[2];
  const float* Wq = (const float*)d_in[3];
  const float* Wk = (const float*)d_in[4];
  const float* Wv = (const float*)d_in[5];
  const float* Wo = (const float*)d_in[6];
  const float* qw = (const float*)d_in[7];
  const float* kw = (const float*)d_in[8];
  const float* Wr = (const float*)d_in[9];
  const float* Wd = (const float*)d_in[10];
  const float* lng = (const float*)d_in[11];
  const float* lnb = (const float*)d_in[12];
  const float* rnn = (const float*)d_in[13];
  float* out = (float*)d_out;

  char* p = (char*)d_ws;
  auto alloc = [&](size_t bytes) { char* r = p; p += (bytes + 255) & ~(size_t)255; return r; };
  bf16* hb    = (bf16*)alloc((size_t)4096 * 2048 * 2);
  bf16* WTall = (bf16*)alloc((size_t)5248 * 2048 * 2);
  bf16* WoT   = (bf16*)alloc((size_t)2048 * 2048 * 2);
  bf16* qgb   = (bf16*)alloc((size_t)4096 * 4096 * 2);
  bf16* kveb  = (bf16*)alloc((size_t)4096 * NKVE * 2);
  bf16* maskb = (bf16*)alloc((size_t)4096 * 128 * 2);
  bf16* wkb   = (bf16*)alloc((size_t)2 * 4 * 2048 * 128 * 2);
  bf16* wvtb  = (bf16*)alloc((size_t)2 * 4 * 128 * 2048 * 2);
  bf16* wab   = (bf16*)alloc((size_t)4096 * 2048 * 2);
  if ((size_t)(p - (char*)d_ws) > ws_size) return;

  prep_weights<<<7744, 256, 0, stream>>>(hidden, Wq, Wk, Wv, Wr, Wo, hb, WTall, WoT);

  // k/v/emb projection: [4096,2048] @ [2048,1152] (m97 structure)
  gemm_bt<bf16><<<288, 256, 0, stream>>>(hb, WTall + (size_t)4096 * 2048, kveb, 4096, NKVE, 2048);

  mask_kernel<<<4096, 128, 0, stream>>>(kveb, rnn, lng, lnb, Wd, maskb);

  // q/gate projection: [4096,2048] @ [2048,4096] (256-squared deep pipeline)
  gemm_qg<<<256, 512, 0, stream>>>(hb, WTall, qgb);

  qkv_prep<<<1536, 256, 0, stream>>>(kveb, maskb, kw, cosT, sinT, wkb, wvtb);

  attn_kernel<<<512, 512, 0, stream>>>(qgb, wkb, wvtb, maskb, qw, cosT, sinT, wab);

  // out projection: [4096,2048] @ [2048,2048] (deep pipeline)
  gemm_out<<<256, 512, 0, stream>>>(wab, WoT, out);
}

// Round 13
// 265.023 us; speedup vs baseline: 1.1213x; 1.1213x over previous
//
#include <hip/hip_runtime.h>
#include <math.h>

typedef __bf16 bf16;
typedef bf16 bf16x8 __attribute__((ext_vector_type(8)));
typedef bf16 bf16x4 __attribute__((ext_vector_type(4)));
typedef float f32x4 __attribute__((ext_vector_type(4)));

#define BB 2
#define SS 2048
#define NKVE 1152   // 512 k + 512 v + 128 emb
#define QSCALE (0.08838834764831845f * 1.4426950408889634f)  // 1/sqrt(128)*log2(e)

__device__ __forceinline__ float waveAllReduceSum(float v) {
#pragma unroll
  for (int o = 1; o < 64; o <<= 1) v += __shfl_xor(v, o, 64);
  return v;
}

__device__ __forceinline__ int xcd_swz(int orig, int nwg) {
  return (orig & 7) * (nwg >> 3) + (orig >> 3);
}

__device__ __forceinline__ void gload16(const bf16* g, bf16* l) {
  __builtin_amdgcn_global_load_lds((const __attribute__((address_space(1))) void*)g,
                                   (__attribute__((address_space(3))) void*)l, 16, 0, 0);
}

// ---------------- fused weight prep: cvt hidden + 5 transposes ----------------
__device__ __forceinline__ void do_transpose(bf16 (*tile)[72], const float* __restrict__ W,
                                             bf16* __restrict__ WT, int K, int N, int rowOff,
                                             int bx, int by, int t) {
  int n0 = bx * 64, k0 = by * 64;
  {
    int c4 = (t & 15) * 4, r = t >> 4;
#pragma unroll
    for (int p = 0; p < 4; p++) {
      int row = p * 16 + r;
      float4 v = *reinterpret_cast<const float4*>(W + (size_t)(k0 + row) * N + n0 + c4);
      bf16x4 o = {(bf16)v.x, (bf16)v.y, (bf16)v.z, (bf16)v.w};
      *reinterpret_cast<bf16x4*>(&tile[row][c4]) = o;
    }
  }
  __syncthreads();
  {
    int ln = t & 7, n = t >> 3;
#pragma unroll
    for (int p = 0; p < 2; p++) {
      int nn = p * 32 + n;
      bf16x8 o;
#pragma unroll
      for (int j = 0; j < 8; j++) o[j] = tile[ln * 8 + j][nn];
      *reinterpret_cast<bf16x8*>(WT + (size_t)(rowOff + n0 + nn) * K + k0 + ln * 8) = o;
    }
  }
  __syncthreads();
}

__global__ __launch_bounds__(256) void prep_weights(const float* __restrict__ hidden,
                                                    const float* __restrict__ Wq,
                                                    const float* __restrict__ Wk,
                                                    const float* __restrict__ Wv,
                                                    const float* __restrict__ Wr,
                                                    const float* __restrict__ Wo,
                                                    bf16* __restrict__ hb,
                                                    bf16* __restrict__ WTall,
                                                    bf16* __restrict__ WoT) {
  __shared__ bf16 tile[64][72];
  int id = blockIdx.x, t = threadIdx.x;
  if (id < 4096) {
    int i = (id * 256 + t) * 8;
    float4 v0 = *reinterpret_cast<const float4*>(hidden + i);
    float4 v1 = *reinterpret_cast<const float4*>(hidden + i + 4);
    bf16x8 o = {(bf16)v0.x, (bf16)v0.y, (bf16)v0.z, (bf16)v0.w,
                (bf16)v1.x, (bf16)v1.y, (bf16)v1.z, (bf16)v1.w};
    *reinterpret_cast<bf16x8*>(hb + i) = o;
    return;
  }
  int id2 = id - 4096;
  if (id2 < 2048) { do_transpose(tile, Wq, WTall, 2048, 4096, 0, id2 & 63, id2 >> 6, t); return; }
  id2 -= 2048;
  if (id2 < 256) { do_transpose(tile, Wk, WTall, 2048, 512, 4096, id2 & 7, id2 >> 3, t); return; }
  id2 -= 256;
  if (id2 < 256) { do_transpose(tile, Wv, WTall, 2048, 512, 4608, id2 & 7, id2 >> 3, t); return; }
  id2 -= 256;
  if (id2 < 64) { do_transpose(tile, Wr, WTall, 2048, 128, 5120, id2 & 1, id2 >> 1, t); return; }
  id2 -= 64;
  do_transpose(tile, Wo, WoT, 2048, 2048, 0, id2 & 31, id2 >> 5, t);
}

// ---------------- m97-style GEMM (kve): C = A @ Bt^T ----------------
template <typename CT>
__global__ __launch_bounds__(256) void gemm_bt(const bf16* __restrict__ A,
                                               const bf16* __restrict__ Bt,
                                               CT* __restrict__ C, int M, int N, int K) {
  __shared__ bf16 lA[128 * 64];
  __shared__ bf16 lB[128 * 64];
  const int nbx = N >> 7;
  int wg = xcd_swz(blockIdx.x, gridDim.x);
  int bx = wg % nbx, by = wg / nbx;
  const int t = threadIdx.x;
  const int l = t & 63, w = t >> 6;
  const int wr = w >> 1, wc = w & 1;
  const int lr = l & 15, lhi = l >> 4;

  f32x4 acc[4][4];
#pragma unroll
  for (int m = 0; m < 4; m++)
#pragma unroll
    for (int n = 0; n < 4; n++) acc[m][n] = f32x4{0.f, 0.f, 0.f, 0.f};

  const int rowA0 = by * 128, rowB0 = bx * 128;
  const int nkt = K >> 6;
  for (int kt = 0; kt < nkt; ++kt) {
    __syncthreads();
#pragma unroll
    for (int it = 0; it < 4; ++it) {
      int slot = it * 256 + t;
      int row = slot >> 3, sl = slot & 7;
      gload16(A + (size_t)(rowA0 + row) * K + kt * 64 + ((sl ^ (row & 7)) << 3), lA + slot * 8);
      gload16(Bt + (size_t)(rowB0 + row) * K + kt * 64 + ((sl ^ (row & 7)) << 3), lB + slot * 8);
    }
    __syncthreads();
#pragma unroll
    for (int kc = 0; kc < 2; ++kc) {
      bf16x8 af[4], bg[4];
#pragma unroll
      for (int m = 0; m < 4; m++) {
        int row = wr * 64 + m * 16 + lr;
        af[m] = *reinterpret_cast<const bf16x8*>((char*)lA + row * 128 + (((kc * 4 + lhi) ^ (row & 7)) << 4));
      }
#pragma unroll
      for (int n = 0; n < 4; n++) {
        int row = wc * 64 + n * 16 + lr;
        bg[n] = *reinterpret_cast<const bf16x8*>((char*)lB + row * 128 + (((kc * 4 + lhi) ^ (row & 7)) << 4));
      }
      __builtin_amdgcn_s_setprio(1);
#pragma unroll
      for (int m = 0; m < 4; m++)
#pragma unroll
        for (int n = 0; n < 4; n++)
          acc[m][n] = __builtin_amdgcn_mfma_f32_16x16x32_bf16(af[m], bg[n], acc[m][n], 0, 0, 0);
      __builtin_amdgcn_s_setprio(0);
    }
  }
#pragma unroll
  for (int m = 0; m < 4; m++)
#pragma unroll
    for (int n = 0; n < 4; n++)
#pragma unroll
      for (int r = 0; r < 4; r++) {
        int grow = rowA0 + wr * 64 + m * 16 + lhi * 4 + r;
        int gcol = rowB0 + wc * 64 + n * 16 + lr;
        C[(size_t)grow * N + gcol] = (CT)acc[m][n][r];
      }
}

// ---------------- q/gate GEMM: 256x256, 8 waves, 2-deep counted-vmcnt pipeline ----------------
__global__ __launch_bounds__(512, 2) void gemm_qg(const bf16* __restrict__ A,
                                                  const bf16* __restrict__ Bt,
                                                  bf16* __restrict__ Cq) {
  __shared__ bf16 lA[2][256 * 64];
  __shared__ bf16 lB[2][256 * 64];
  int wg = xcd_swz(blockIdx.x, 256);
  int bx = wg & 15, by = wg >> 4;
  const int t = threadIdx.x;
  const int l = t & 63, w = t >> 6;
  const int wm = w >> 2, wn = w & 3;
  const int lr = l & 15, lhi = l >> 4;
  const int K = 2048;

  f32x4 acc[8][4];
#pragma unroll
  for (int m = 0; m < 8; m++)
#pragma unroll
    for (int n = 0; n < 4; n++) acc[m][n] = f32x4{0.f, 0.f, 0.f, 0.f};

  const int rowA0 = by * 256, rowB0 = bx * 256;

  auto stage = [&](int buf, int kt) {
#pragma unroll
    for (int it = 0; it < 4; ++it) {
      int slot = it * 512 + t;
      int row = slot >> 3, sl = slot & 7;
      gload16(A + (size_t)(rowA0 + row) * K + kt * 64 + ((sl ^ (row & 7)) << 3), lA[buf] + slot * 8);
      gload16(Bt + (size_t)(rowB0 + row) * K + kt * 64 + ((sl ^ (row & 7)) << 3), lB[buf] + slot * 8);
    }
  };

  stage(0, 0);
  stage(1, 1);

  for (int kt = 0; kt < 32; ++kt) {
    int cur = kt & 1;
    if (kt < 31) {
      asm volatile("s_waitcnt vmcnt(8)" ::: "memory");
    } else {
      asm volatile("s_waitcnt vmcnt(0)" ::: "memory");
    }
    __builtin_amdgcn_sched_barrier(0);
    __builtin_amdgcn_s_barrier();
    __builtin_amdgcn_sched_barrier(0);

#pragma unroll
    for (int ks = 0; ks < 2; ++ks) {
      bf16x8 bg[4];
#pragma unroll
      for (int n = 0; n < 4; n++) {
        int row = wn * 64 + n * 16 + lr;
        bg[n] = *reinterpret_cast<const bf16x8*>((char*)lB[cur] + row * 128 + (((ks * 4 + lhi) ^ (row & 7)) << 4));
      }
#pragma unroll
      for (int mh = 0; mh < 2; ++mh) {
        bf16x8 af[4];
#pragma unroll
        for (int m = 0; m < 4; m++) {
          int row = wm * 128 + (mh * 4 + m) * 16 + lr;
          af[m] = *reinterpret_cast<const bf16x8*>((char*)lA[cur] + row * 128 + (((ks * 4 + lhi) ^ (row & 7)) << 4));
        }
        __builtin_amdgcn_s_setprio(1);
#pragma unroll
        for (int m = 0; m < 4; m++)
#pragma unroll
          for (int n = 0; n < 4; n++)
            acc[mh * 4 + m][n] = __builtin_amdgcn_mfma_f32_16x16x32_bf16(af[m], bg[n], acc[mh * 4 + m][n], 0, 0, 0);
        __builtin_amdgcn_s_setprio(0);
      }
    }

    asm volatile("s_waitcnt lgkmcnt(0)" ::: "memory");
    __builtin_amdgcn_sched_barrier(0);
    __builtin_amdgcn_s_barrier();
    __builtin_amdgcn_sched_barrier(0);
    if (kt + 2 < 32) stage(cur, kt + 2);
  }

#pragma unroll
  for (int m = 0; m < 8; m++)
#pragma unroll
    for (int n = 0; n < 4; n++)
#pragma unroll
      for (int r = 0; r < 4; r++) {
        int grow = rowA0 + wm * 128 + m * 16 + lhi * 4 + r;
        int gcol = rowB0 + wn * 64 + n * 16 + lr;
        Cq[(size_t)grow * 4096 + gcol] = (bf16)acc[m][n][r];
      }
}

// ---------------- out GEMM: 256x128, 8 waves, 2-deep counted-vmcnt pipeline ----------------
__global__ __launch_bounds__(512, 2) void gemm_out(const bf16* __restrict__ A,
                                                   const bf16* __restrict__ Bt,
                                                   float* __restrict__ C) {
  __shared__ bf16 lA[2][256 * 64];
  __shared__ bf16 lB[2][128 * 64];
  int wg = xcd_swz(blockIdx.x, 256);
  int bx = wg & 15, by = wg >> 4;
  const int t = threadIdx.x;
  const int l = t & 63, w = t >> 6;
  const int wm = w >> 1, wn = w & 1;
  const int lr = l & 15, lhi = l >> 4;
  const int K = 2048;

  f32x4 acc[4][4];
#pragma unroll
  for (int m = 0; m < 4; m++)
#pragma unroll
    for (int n = 0; n < 4; n++) acc[m][n] = f32x4{0.f, 0.f, 0.f, 0.f};

  const int rowA0 = by * 256, rowB0 = bx * 128;

  auto stage = [&](int buf, int kt) {
#pragma unroll
    for (int it = 0; it < 4; ++it) {
      int slot = it * 512 + t;
      int row = slot >> 3, sl = slot & 7;
      gload16(A + (size_t)(rowA0 + row) * K + kt * 64 + ((sl ^ (row & 7)) << 3), lA[buf] + slot * 8);
    }
#pragma unroll
    for (int it = 0; it < 2; ++it) {
      int slot = it * 512 + t;
      int row = slot >> 3, sl = slot & 7;
      gload16(Bt + (size_t)(rowB0 + row) * K + kt * 64 + ((sl ^ (row & 7)) << 3), lB[buf] + slot * 8);
    }
  };

  stage(0, 0);
  stage(1, 1);

  for (int kt = 0; kt < 32; ++kt) {
    int cur = kt & 1;
    if (kt < 31) {
      asm volatile("s_waitcnt vmcnt(6)" ::: "memory");
    } else {
      asm volatile("s_waitcnt vmcnt(0)" ::: "memory");
    }
    __builtin_amdgcn_sched_barrier(0);
    __builtin_amdgcn_s_barrier();
    __builtin_amdgcn_sched_barrier(0);

#pragma unroll
    for (int ks = 0; ks < 2; ++ks) {
      bf16x8 bg[4];
#pragma unroll
      for (int n = 0; n < 4; n++) {
        int row = wn * 64 + n * 16 + lr;
        bg[n] = *reinterpret_cast<const bf16x8*>((char*)lB[cur] + row * 128 + (((ks * 4 + lhi) ^ (row & 7)) << 4));
      }
      bf16x8 af[4];
#pragma unroll
      for (int m = 0; m < 4; m++) {
        int row = wm * 64 + m * 16 + lr;
        af[m] = *reinterpret_cast<const bf16x8*>((char*)lA[cur] + row * 128 + (((ks * 4 + lhi) ^ (row & 7)) << 4));
      }
      __builtin_amdgcn_s_setprio(1);
#pragma unroll
      for (int m = 0; m < 4; m++)
#pragma unroll
        for (int n = 0; n < 4; n++)
          acc[m][n] = __builtin_amdgcn_mfma_f32_16x16x32_bf16(af[m], bg[n], acc[m][n], 0, 0, 0);
      __builtin_amdgcn_s_setprio(0);
    }

    asm volatile("s_waitcnt lgkmcnt(0)" ::: "memory");
    __builtin_amdgcn_sched_barrier(0);
    __builtin_amdgcn_s_barrier();
    __builtin_amdgcn_sched_barrier(0);
    if (kt + 2 < 32) stage(cur, kt + 2);
  }

#pragma unroll
  for (int m = 0; m < 4; m++)
#pragma unroll
    for (int n = 0; n < 4; n++)
#pragma unroll
      for (int r = 0; r < 4; r++) {
        int grow = rowA0 + wm * 64 + m * 16 + lhi * 4 + r;
        int gcol = rowB0 + wn * 64 + n * 16 + lr;
        C[(size_t)grow * 2048 + gcol] = acc[m][n][r];
      }
}

// ---------------- Threefry-2x32 (JAX), key (0,42) -> gumbel ----------------
__device__ __forceinline__ unsigned rotl32(unsigned x, int r) { return (x << r) | (x >> (32 - r)); }

__device__ __forceinline__ float gumbel42(unsigned i) {
  const unsigned half = (unsigned)(BB * SS * 128) / 2u;  // 262144
  unsigned x0, x1;
  int word;
  if (i < half) { x0 = i; x1 = i + half; word = 0; }
  else          { x0 = i - half; x1 = i; word = 1; }
  const unsigned k0 = 0u, k1 = 42u;
  const unsigned k2 = k0 ^ k1 ^ 0x1BD11BDAu;
  x0 += k0; x1 += k1;
#define TF_R(r) { x0 += x1; x1 = rotl32(x1, r); x1 ^= x0; }
  TF_R(13) TF_R(15) TF_R(26) TF_R(6)
  x0 += k1; x1 += k2 + 1u;
  TF_R(17) TF_R(29) TF_R(16) TF_R(24)
  x0 += k2; x1 += k0 + 2u;
  TF_R(13) TF_R(15) TF_R(26) TF_R(6)
  x0 += k0; x1 += k1 + 3u;
  TF_R(17) TF_R(29) TF_R(16) TF_R(24)
  x0 += k1; x1 += k2 + 4u;
  TF_R(13) TF_R(15) TF_R(26) TF_R(6)
  x0 += k2; x1 += k0 + 5u;
#undef TF_R
  unsigned bits = word ? x1 : x0;
  float u = __uint_as_float((bits >> 9) | 0x3f800000u) - 1.0f;
  float ex = -log1pf(-u);
  return -logf(ex);
}

// ---------------- mask kernel (reads emb from kve[.., 1024..1151]) ----------------
__global__ __launch_bounds__(128) void mask_kernel(const bf16* __restrict__ kve,
                                                   const float* __restrict__ rnn,
                                                   const float* __restrict__ lng,
                                                   const float* __restrict__ lnb,
                                                   const float* __restrict__ Wd,
                                                   bf16* __restrict__ maskb) {
  int row = blockIdx.x;
  int t = threadIdx.x;
  int l = t & 63, w = t >> 6;
  __shared__ float redm[2], redv[2], gsh[128];
  float e = (float)kve[(size_t)row * NKVE + 1024 + t] + rnn[t];
  float s1 = waveAllReduceSum(e);
  if (l == 0) redm[w] = s1;
  __syncthreads();
  float mu = (redm[0] + redm[1]) * (1.0f / 128.0f);
  float dv = (e - mu) * (e - mu);
  float s2 = waveAllReduceSum(dv);
  if (l == 0) redv[w] = s2;
  __syncthreads();
  float var = (redv[0] + redv[1]) * (1.0f / 128.0f);
  float ln = (e - mu) * rsqrtf(var + 1e-5f) * lng[t] + lnb[t];
  float g = 0.5f * ln * (1.0f + erff(ln * 0.7071067811865475f));
  gsh[t] = g;
  __syncthreads();
  float logit = 0.f;
#pragma unroll 8
  for (int e2 = 0; e2 < 128; e2++) logit += gsh[e2] * Wd[e2 * 128 + t];
  float gum = gumbel42((unsigned)(row * 128 + t));
  float x = (logit + gum + 3.0f) * 2.5f;
  float y = 1.0f / (1.0f + expf(-x));
  maskb[(size_t)row * 128 + t] = (bf16)rintf(y);
}

// ---------------- QKV prep (k + vt from kve) ----------------
__global__ __launch_bounds__(256) void qkv_prep(const bf16* __restrict__ kve,
                                                const bf16* __restrict__ maskb,
                                                const float* __restrict__ kw,
                                                const float* __restrict__ cosT,
                                                const float* __restrict__ sinT,
                                                bf16* __restrict__ wk,
                                                bf16* __restrict__ wvt) {
  int id = blockIdx.x, t = threadIdx.x;
  if (id < 1024) {
    int g = t >> 4, ln = t & 15;
    int hr = id * 16 + g;
    int kv = hr & 3, row = hr >> 2;
    int b = row >> 11, s = row & 2047;
    const bf16* kp = kve + (size_t)row * NKVE + kv * 128 + ln * 8;
    bf16x8 k8 = *reinterpret_cast<const bf16x8*>(kp);
    bf16x8 m8 = *reinterpret_cast<const bf16x8*>(maskb + (size_t)row * 128 + ln * 8);
    float kf[8], ss = 0.f;
#pragma unroll
    for (int j = 0; j < 8; j++) { kf[j] = (float)k8[j]; ss += kf[j] * kf[j]; }
#pragma unroll
    for (int o = 1; o < 16; o <<= 1) ss += __shfl_xor(ss, o, 16);
    float rinv = rsqrtf(ss * (1.0f / 128.0f) + 1e-6f);
    alignas(16) float wv[8];
    const float4* kw4 = reinterpret_cast<const float4*>(kw);
    *reinterpret_cast<float4*>(&wv[0]) = kw4[ln * 2];
    *reinterpret_cast<float4*>(&wv[4]) = kw4[ln * 2 + 1];
    float km[8];
#pragma unroll
    for (int j = 0; j < 8; j++) km[j] = kf[j] * rinv * (1.0f + wv[j]) * (float)m8[j];
    alignas(16) float c8[8], s8[8];
    if (ln < 8) {
      const float4* c4 = reinterpret_cast<const float4*>(cosT + (size_t)row * 64);
      const float4* sn4 = reinterpret_cast<const float4*>(sinT + (size_t)row * 64);
      *reinterpret_cast<float4*>(&c8[0]) = c4[ln * 2];
      *reinterpret_cast<float4*>(&c8[4]) = c4[ln * 2 + 1];
      *reinterpret_cast<float4*>(&s8[0]) = sn4[ln * 2];
      *reinterpret_cast<float4*>(&s8[4]) = sn4[ln * 2 + 1];
    }
    float po[8];
#pragma unroll
    for (int j = 0; j < 8; j++) po[j] = __shfl_xor(km[j], 4, 16);
    bf16x8 ok;
#pragma unroll
    for (int j = 0; j < 8; j++) {
      float ov;
      if (ln < 4) ov = km[j] * c8[j] - po[j] * s8[j];
      else if (ln < 8) ov = km[j] * c8[j] + po[j] * s8[j];
      else ov = km[j];
      ok[j] = (bf16)ov;
    }
    *reinterpret_cast<bf16x8*>(wk + ((size_t)((b * 4 + kv) * 2048 + s)) * 128 + ln * 8) = ok;
    return;
  }
  {
    __shared__ bf16 tl[64][72];
    int vb = id - 1024;
    int dt = vb & 1;
    int st = (vb >> 1) & 31;
    int bkv = vb >> 6;
    int b = bkv >> 2, kv = bkv & 3;
    int tx = t & 63, ty = t >> 6;
    int s0 = st * 64, d0 = dt * 64;
#pragma unroll
    for (int i = 0; i < 16; i++) {
      int srow = ty + i * 4;
      tl[srow][tx] = kve[(size_t)(b * 2048 + s0 + srow) * NKVE + 512 + kv * 128 + d0 + tx];
    }
    __syncthreads();
#pragma unroll
    for (int i = 0; i < 16; i++) {
      int drow = ty + i * 4;
      wvt[(size_t)((b * 4 + kv) * 128 + d0 + drow) * 2048 + s0 + tx] = tl[tx][drow];
    }
  }
}

// ---------------- flash attention (r10 structure): 256 blocks, paired q128 halves, dbuf,
// absolute staging addresses, in-register Q prep, no-shift softmax ----------------
__global__ __launch_bounds__(512) void attn_kernel(const bf16* __restrict__ qg,
                                                   const bf16* __restrict__ wk,
                                                   const bf16* __restrict__ wvt,
                                                   const bf16* __restrict__ maskb,
                                                   const float* __restrict__ qw,
                                                   const float* __restrict__ cosT,
                                                   const float* __restrict__ sinT,
                                                   bf16* __restrict__ wattn) {
  __shared__ bf16 lK[2][64 * 128];
  __shared__ bf16 lV[2][128 * 64];
  __shared__ bf16 lP[8][16 * 64];
  int bid = blockIdx.x;
  int grp = bid & 7;          // XCD group = b*4+kvh
  int b = grp >> 2, kvh = grp & 3;
  int g32 = bid >> 3;         // 0..31 within group
  int pp = g32 & 7;           // q128-pair index: halves (pp, 15-pp)
  int h = kvh * 4 + (g32 >> 3);
  int bh = b * 16 + h;
  int t = threadIdx.x, l = t & 63, w = t >> 6;
  int lr = l & 15, lhi = l >> 4;

  const bf16* kbase = wk + (size_t)((b * 4 + kvh) * 2048) * 128;
  const bf16* vbase = wvt + (size_t)((b * 4 + kvh) * 128) * 2048;
  char* pb = (char*)(&lP[w][0]);

  const int n0 = 2 * pp + 2;  // tiles for half 0; half 1 has 32-2*pp; total 34

  auto stage = [&](int buf, int tt) {
#pragma unroll
    for (int it = 0; it < 2; ++it) {
      int slot = it * 512 + t;
      int row = slot >> 4, sl = slot & 15;
      gload16(kbase + (size_t)(tt * 64 + row) * 128 + ((sl ^ (row & 7)) << 3), lK[buf] + slot * 8);
      int row2 = slot >> 3, sl2 = slot & 7;
      gload16(vbase + (size_t)row2 * 2048 + tt * 64 + ((sl2 ^ (row2 & 7)) << 3), lV[buf] + slot * 8);
    }
  };

  bf16x8 aq[4];
  f32x4 oacc[8];
  float l_run;
  int qb128 = pp;

  auto load_q = [&](int qbv) {
    int srow = qbv * 128 + w * 16 + lr;
    int grow = b * 2048 + srow;
    const bf16* qp = qg + (size_t)grow * 4096 + h * 256;
    int dbase = lhi * 8;
    float qf[4][8];
    float ss = 0.f;
#pragma unroll
    for (int kc = 0; kc < 4; kc++) {
      bf16x8 v = *reinterpret_cast<const bf16x8*>(qp + kc * 32 + dbase);
#pragma unroll
      for (int j = 0; j < 8; j++) { qf[kc][j] = (float)v[j]; ss += qf[kc][j] * qf[kc][j]; }
    }
    ss += __shfl_xor(ss, 16, 64);
    ss += __shfl_xor(ss, 32, 64);
    float rinv = rsqrtf(ss * (1.0f / 128.0f) + 1e-6f);
    const bf16* mrow = maskb + (size_t)grow * 128;
    float qm[4][8];
#pragma unroll
    for (int kc = 0; kc < 4; kc++) {
      bf16x8 m8 = *reinterpret_cast<const bf16x8*>(mrow + kc * 32 + dbase);
      alignas(16) float wv[8];
      *reinterpret_cast<float4*>(&wv[0]) = *reinterpret_cast<const float4*>(qw + kc * 32 + dbase);
      *reinterpret_cast<float4*>(&wv[4]) = *reinterpret_cast<const float4*>(qw + kc * 32 + dbase + 4);
#pragma unroll
      for (int j = 0; j < 8; j++) qm[kc][j] = qf[kc][j] * rinv * (1.0f + wv[j]) * (float)m8[j];
    }
    const float* crow = cosT + (size_t)grow * 64;
    const float* srw = sinT + (size_t)grow * 64;
    alignas(16) float c0[8], c1[8], s0[8], s1[8];
    *reinterpret_cast<float4*>(&c0[0]) = *reinterpret_cast<const float4*>(crow + dbase);
    *reinterpret_cast<float4*>(&c0[4]) = *reinterpret_cast<const float4*>(crow + dbase + 4);
    *reinterpret_cast<float4*>(&c1[0]) = *reinterpret_cast<const float4*>(crow + 32 + dbase);
    *reinterpret_cast<float4*>(&c1[4]) = *reinterpret_cast<const float4*>(crow + 32 + dbase + 4);
    *reinterpret_cast<float4*>(&s0[0]) = *reinterpret_cast<const float4*>(srw + dbase);
    *reinterpret_cast<float4*>(&s0[4]) = *reinterpret_cast<const float4*>(srw + dbase + 4);
    *reinterpret_cast<float4*>(&s1[0]) = *reinterpret_cast<const float4*>(srw + 32 + dbase);
    *reinterpret_cast<float4*>(&s1[4]) = *reinterpret_cast<const float4*>(srw + 32 + dbase + 4);
#pragma unroll
    for (int j = 0; j < 8; j++) {
      float o0 = qm[0][j] * c0[j] - qm[1][j] * s0[j];
      float o1 = qm[1][j] * c1[j] + qm[0][j] * s1[j];
      aq[0][j] = (bf16)(o0 * QSCALE);
      aq[1][j] = (bf16)(o1 * QSCALE);
      aq[2][j] = (bf16)(qm[2][j] * QSCALE);
      aq[3][j] = (bf16)(qm[3][j] * QSCALE);
    }
  };

  load_q(pp);
#pragma unroll
  for (int db = 0; db < 8; db++) oacc[db] = f32x4{0.f, 0.f, 0.f, 0.f};
  l_run = 0.f;

  stage(0, 0);
  __syncthreads();
  int cur = 0;

  for (int i = 0; i < 34; ++i) {
    int tt = (i < n0) ? i : i - n0;
    if (i + 1 < 34) {
      int tn = (i + 1 < n0) ? (i + 1) : (i + 1 - n0);
      stage(cur ^ 1, tn);
    }
    int qrow0 = qb128 * 128 + w * 16;

    // QK^T (swapped): S[k local][q = lr]
    f32x4 sacc[4];
#pragma unroll
    for (int j = 0; j < 4; j++) sacc[j] = f32x4{0.f, 0.f, 0.f, 0.f};
    __builtin_amdgcn_s_setprio(1);
#pragma unroll
    for (int kc = 0; kc < 4; kc++)
#pragma unroll
      for (int j = 0; j < 4; j++) {
        int row = j * 16 + lr;
        bf16x8 ak = *reinterpret_cast<const bf16x8*>((char*)lK[cur] + row * 256 + (((kc * 4 + lhi) ^ (row & 7)) << 4));
        sacc[j] = __builtin_amdgcn_mfma_f32_16x16x32_bf16(ak, aq[kc], sacc[j], 0, 0, 0);
      }
    __builtin_amdgcn_s_setprio(0);

    if (tt * 64 + 63 > qrow0) {  // causal mask
      int qrow_g = qrow0 + lr;
#pragma unroll
      for (int j = 0; j < 4; j++)
#pragma unroll
        for (int r = 0; r < 4; r++) {
          int kg = tt * 64 + j * 16 + lhi * 4 + r;
          if (kg > qrow_g) sacc[j][r] = -1e30f;
        }
    }

    // unshifted softmax numerator: |S| <= sqrt(128)*log2e = 16.4 strictly, exp2 safe
    float p[4][4];
    float sj[4];
#pragma unroll
    for (int j = 0; j < 4; j++) {
#pragma unroll
      for (int r = 0; r < 4; r++) p[j][r] = exp2f(sacc[j][r]);
      sj[j] = (p[j][0] + p[j][1]) + (p[j][2] + p[j][3]);
    }
    l_run += (sj[0] + sj[1]) + (sj[2] + sj[3]);

    // P through per-wave LDS (swizzled), then PV
#pragma unroll
    for (int j = 0; j < 4; j++) {
      bf16x4 p4 = {(bf16)p[j][0], (bf16)p[j][1], (bf16)p[j][2], (bf16)p[j][3]};
      *reinterpret_cast<bf16x4*>(pb + lr * 128 + ((j * 32 + lhi * 8) ^ ((lr & 7) << 4))) = p4;
    }
    bf16x8 pa[2];
#pragma unroll
    for (int kc2 = 0; kc2 < 2; kc2++)
      pa[kc2] = *reinterpret_cast<const bf16x8*>(pb + lr * 128 + ((kc2 * 64 + lhi * 16) ^ ((lr & 7) << 4)));
    __builtin_amdgcn_s_setprio(1);
#pragma unroll
    for (int kc2 = 0; kc2 < 2; kc2++)
#pragma unroll
      for (int db = 0; db < 8; db++) {
        int row = db * 16 + lr;
        bf16x8 bv = *reinterpret_cast<const bf16x8*>((char*)lV[cur] + row * 128 + (((kc2 * 4 + lhi) ^ (row & 7)) << 4));
        oacc[db] = __builtin_amdgcn_mfma_f32_16x16x32_bf16(pa[kc2], bv, oacc[db], 0, 0, 0);
      }
    __builtin_amdgcn_s_setprio(0);

    if (i == n0 - 1 || i == 33) {  // end of a half: reduce l, epilogue (raw gate from qg)
      float lsum = l_run;
      lsum += __shfl_xor(lsum, 16, 64);
      lsum += __shfl_xor(lsum, 32, 64);
      float linv[4];
#pragma unroll
      for (int r = 0; r < 4; r++) linv[r] = 1.0f / __shfl(lsum, lhi * 4 + r, 64);
#pragma unroll
      for (int r = 0; r < 4; r++) {
        int srow = qb128 * 128 + w * 16 + lhi * 4 + r;
        const bf16* grow_p = qg + (size_t)(b * 2048 + srow) * 4096 + h * 256 + 128;
#pragma unroll
        for (int db = 0; db < 8; db++) {
          int dcol = db * 16 + lr;
          float graw = (float)grow_p[dcol];
          float g = 1.0f / (1.0f + expf(-graw));
          float ov = oacc[db][r] * linv[r] * g;
          wattn[(size_t)(b * 2048 + srow) * 2048 + h * 128 + dcol] = (bf16)ov;
        }
      }
      if (i == n0 - 1) {
        qb128 = 15 - pp;
        load_q(qb128);
#pragma unroll
        for (int db = 0; db < 8; db++) oacc[db] = f32x4{0.f, 0.f, 0.f, 0.f};
        l_run = 0.f;
      }
    }

    __syncthreads();
    cur ^= 1;
  }
}

extern "C" void kernel_launch(void* const* d_in, const int* in_sizes, int n_in,
                              void* d_out, int out_size, void* d_ws, size_t ws_size,
                              hipStream_t stream) {
  const float* hidden = (const float*)d_in[0];
  const float* cosT = (const float*)d_in[1];
  const float* sinT = (const float*)d_in[2];
  const float* Wq = (const float*)d_in[3];
  const float* Wk = (const float*)d_in[4];
  const float* Wv = (const float*)d_in[5];
  const float* Wo = (const float*)d_in[6];
  const float* qw = (const float*)d_in[7];
  const float* kw = (const float*)d_in[8];
  const float* Wr = (const float*)d_in[9];
  const float* Wd = (const float*)d_in[10];
  const float* lng = (const float*)d_in[11];
  const float* lnb = (const float*)d_in[12];
  const float* rnn = (const float*)d_in[13];
  float* out = (float*)d_out;

  char* p = (char*)d_ws;
  auto alloc = [&](size_t bytes) { char* r = p; p += (bytes + 255) & ~(size_t)255; return r; };
  bf16* hb    = (bf16*)alloc((size_t)4096 * 2048 * 2);
  bf16* WTall = (bf16*)alloc((size_t)5248 * 2048 * 2);
  bf16* WoT   = (bf16*)alloc((size_t)2048 * 2048 * 2);
  bf16* qgb   = (bf16*)alloc((size_t)4096 * 4096 * 2);
  bf16* kveb  = (bf16*)alloc((size_t)4096 * NKVE * 2);
  bf16* maskb = (bf16*)alloc((size_t)4096 * 128 * 2);
  bf16* wkb   = (bf16*)alloc((size_t)2 * 4 * 2048 * 128 * 2);
  bf16* wvtb  = (bf16*)alloc((size_t)2 * 4 * 128 * 2048 * 2);
  bf16* wab   = (bf16*)alloc((size_t)4096 * 2048 * 2);
  if ((size_t)(p - (char*)d_ws) > ws_size) return;

  prep_weights<<<7744, 256, 0, stream>>>(hidden, Wq, Wk, Wv, Wr, Wo, hb, WTall, WoT);

  // k/v/emb projection: [4096,2048] @ [2048,1152] (m97 structure)
  gemm_bt<bf16><<<288, 256, 0, stream>>>(hb, WTall + (size_t)4096 * 2048, kveb, 4096, NKVE, 2048);

  mask_kernel<<<4096, 128, 0, stream>>>(kveb, rnn, lng, lnb, Wd, maskb);

  // q/gate projection: [4096,2048] @ [2048,4096] (256-squared deep pipeline)
  gemm_qg<<<256, 512, 0, stream>>>(hb, WTall, qgb);

  qkv_prep<<<1536, 256, 0, stream>>>(kveb, maskb, kw, cosT, sinT, wkb, wvtb);

  attn_kernel<<<256, 512, 0, stream>>>(qgb, wkb, wvtb, maskb, qw, cosT, sinT, wab);

  // out projection: [4096,2048] @ [2048,2048] (deep pipeline)
  gemm_out<<<256, 512, 0, stream>>>(wab, WoT, out);
}